// Round 17
// baseline (182.725 us; speedup 1.0000x reference)
//
#include <hip/hip_runtime.h>
#include <hip/hip_fp16.h>

#define N_NODES 100000
#define N_EDGES 1600000
#define NPART 98           // partitions of 1024 nodes
#define CAP   20480        // bucket capacity
#define EB    8192         // edges per binc block
#define NBB   ((N_EDGES + EB - 1) / EB)        // 196
#define NBT   ((N_NODES + 127) / 128)          // 782

typedef _Float16 half8 __attribute__((ext_vector_type(8)));
typedef float f32x4 __attribute__((ext_vector_type(4)));

// ---------------- workspace layout (bytes) ----------------
#define WS_OFF   0          // int[N+1]
#define WS_PCUR  400016     // int[128]
#define WS_SJ    401040     // int[E]           (6.4 MB)
#define WS_BCOMB 6817424    // float[64]
#define WS_PK    6817680    // _Float16[5*4096] (40 KB)
#define WS_Q     6858640    // _Float16[N*64]   (12.8 MB)
#define WS_BIN   19658640   // int[NPART*CAP]   (8.0 MB)

// ---- K1: weight packing (wcomb inline) + bcomb + pcur init ----
__global__ void __launch_bounds__(256) k_setup(const float* __restrict__ mw1,
                                               const float* __restrict__ mw2,
                                               const float* __restrict__ mb2,
                                               const float* __restrict__ aw1,
                                               const float* __restrict__ aw2,
                                               _Float16* __restrict__ pk,
                                               float* __restrict__ bcomb,
                                               int* __restrict__ pcur) {
    __shared__ float wc[4096];
    int blk = blockIdx.x, t = threadIdx.x;
    if (blk < 5) {
        const float* src;
        if (blk == 3) {
            for (int o = t; o < 4096; o += 256) {
                int c = o >> 6, k = o & 63;
                float s = 0.f;
                #pragma unroll 8
                for (int a = 0; a < 64; ++a) s += mw2[c * 64 + a] * aw1[(64 + a) * 64 + k];
                wc[o] = s;
            }
            __syncthreads();
            src = wc;
        } else {
            src = (blk == 0) ? mw1 : (blk == 1) ? (mw1 + 4096)
                : (blk == 2) ? aw1 : aw2;
        }
        _Float16* dst = pk + blk * 4096;
        for (int o = t; o < 4096; o += 256) {
            int b_ = o & 7, l = (o >> 3) & 63, z = o >> 9;
            int kg = z & 1, nt = z >> 1;
            int k = kg * 32 + ((l >> 4) << 3) + b_;
            int n = nt * 16 + (l & 15);
            dst[o] = (_Float16)src[k * 64 + n];
        }
    } else {
        if (t < 64) {
            float s = 0.f;
            #pragma unroll 8
            for (int a = 0; a < 64; ++a) s += mb2[a] * aw1[(64 + a) * 64 + t];
            bcomb[t] = s;
        }
        if (t < 128) pcur[t] = t * CAP;
    }
}

// ---- MFMA helpers ----
__device__ __forceinline__ half8 afrag_f32(const float* src, int row, int kg, int l) {
    const float* p = src + (size_t)row * 64 + kg * 32 + ((l >> 4) << 3);
    float4 u = *(const float4*)p;
    float4 v = *(const float4*)(p + 4);
    half8 h;
    h[0] = (_Float16)u.x; h[1] = (_Float16)u.y; h[2] = (_Float16)u.z; h[3] = (_Float16)u.w;
    h[4] = (_Float16)v.x; h[5] = (_Float16)v.y; h[6] = (_Float16)v.z; h[7] = (_Float16)v.w;
    return h;
}

// ---- K2: binc (blocks 0..NBB-1)  ||  pre (blocks NBB..NBB+NBT-1) ----
__global__ void __launch_bounds__(256) k_binpre(const int* __restrict__ ei,
                                                const int* __restrict__ ej,
                                                int* pcur, int* __restrict__ binned,
                                                const float* __restrict__ x,
                                                const float* __restrict__ pos,
                                                const float* __restrict__ mw1,
                                                const float* __restrict__ mb1,
                                                const _Float16* __restrict__ pk,
                                                float* __restrict__ P,
                                                _Float16* __restrict__ Q16) {
    __shared__ int cnt[NPART];
    __shared__ int wcur[NPART];
    int t = threadIdx.x;
    if (blockIdx.x < NBB) {
        for (int q = t; q < NPART; q += 256) cnt[q] = 0;
        __syncthreads();
        int base_e = blockIdx.x * EB;
        #pragma unroll 2
        for (int it = 0; it < EB / 1024; ++it) {
            int e = base_e + it * 1024 + t * 4;
            if (e < N_EDGES) {
                int4 iv = *(const int4*)(ei + e);
                atomicAdd(&cnt[iv.x >> 10], 1);
                atomicAdd(&cnt[iv.y >> 10], 1);
                atomicAdd(&cnt[iv.z >> 10], 1);
                atomicAdd(&cnt[iv.w >> 10], 1);
            }
        }
        __syncthreads();
        for (int q = t; q < NPART; q += 256)
            wcur[q] = cnt[q] ? atomicAdd(&pcur[q], cnt[q]) : 0;
        __syncthreads();
        #pragma unroll 2
        for (int it = 0; it < EB / 1024; ++it) {
            int e = base_e + it * 1024 + t * 4;
            if (e < N_EDGES) {
                int4 iv = *(const int4*)(ei + e);
                int4 jv = *(const int4*)(ej + e);
                int a, p;
                p = iv.x >> 10; a = atomicAdd(&wcur[p], 1);
                if (a < (p + 1) * CAP) binned[a] = ((iv.x & 1023) << 17) | jv.x;
                p = iv.y >> 10; a = atomicAdd(&wcur[p], 1);
                if (a < (p + 1) * CAP) binned[a] = ((iv.y & 1023) << 17) | jv.y;
                p = iv.z >> 10; a = atomicAdd(&wcur[p], 1);
                if (a < (p + 1) * CAP) binned[a] = ((iv.z & 1023) << 17) | jv.z;
                p = iv.w >> 10; a = atomicAdd(&wcur[p], 1);
                if (a < (p + 1) * CAP) binned[a] = ((iv.w & 1023) << 17) | jv.w;
            }
        }
        return;
    }
    // ---- pre: P' = x@W1a + mb1 - pos@W1p (fp32); Q' = x@W1b + pos@W1p (fp16) ----
    int bid = blockIdx.x - NBB;
    int w = t >> 6, l = t & 63;
    int m0 = bid * 128 + w * 32;

    half8 a[2][2];
    #pragma unroll
    for (int s = 0; s < 2; ++s)
        #pragma unroll
        for (int kg = 0; kg < 2; ++kg) {
            int row = m0 + s * 16 + (l & 15);
            if (row >= N_NODES) row = N_NODES - 1;
            a[s][kg] = afrag_f32(x, row, kg, l);
        }

    f32x4 z = {0.f, 0.f, 0.f, 0.f};
    f32x4 accP[2][4], accQ[2][4];
    #pragma unroll
    for (int s = 0; s < 2; ++s)
        #pragma unroll
        for (int nt = 0; nt < 4; ++nt) { accP[s][nt] = z; accQ[s][nt] = z; }

    #pragma unroll
    for (int nt = 0; nt < 4; ++nt)
        #pragma unroll
        for (int kg = 0; kg < 2; ++kg) {
            half8 b = *(const half8*)(pk + ((nt * 2 + kg) * 64 + l) * 8);
            accP[0][nt] = __builtin_amdgcn_mfma_f32_16x16x32_f16(a[0][kg], b, accP[0][nt], 0, 0, 0);
            accP[1][nt] = __builtin_amdgcn_mfma_f32_16x16x32_f16(a[1][kg], b, accP[1][nt], 0, 0, 0);
        }
    const _Float16* pkb = pk + 4096;
    #pragma unroll
    for (int nt = 0; nt < 4; ++nt)
        #pragma unroll
        for (int kg = 0; kg < 2; ++kg) {
            half8 b = *(const half8*)(pkb + ((nt * 2 + kg) * 64 + l) * 8);
            accQ[0][nt] = __builtin_amdgcn_mfma_f32_16x16x32_f16(a[0][kg], b, accQ[0][nt], 0, 0, 0);
            accQ[1][nt] = __builtin_amdgcn_mfma_f32_16x16x32_f16(a[1][kg], b, accQ[1][nt], 0, 0, 0);
        }

    int col = l & 15;
    float wx[4], wy[4], wz[4], bb[4];
    #pragma unroll
    for (int nt = 0; nt < 4; ++nt) {
        int n = nt * 16 + col;
        wx[nt] = mw1[128 * 64 + n];
        wy[nt] = mw1[129 * 64 + n];
        wz[nt] = mw1[130 * 64 + n];
        bb[nt] = mb1[n];
    }
    #pragma unroll
    for (int s = 0; s < 2; ++s)
        #pragma unroll
        for (int r = 0; r < 4; ++r) {
            int m = m0 + s * 16 + ((l >> 4) << 2) + r;
            if (m >= N_NODES) continue;
            float px = pos[3 * m], py = pos[3 * m + 1], pz = pos[3 * m + 2];
            #pragma unroll
            for (int nt = 0; nt < 4; ++nt) {
                int n = nt * 16 + col;
                float pd = px * wx[nt] + py * wy[nt] + pz * wz[nt];
                P[(size_t)m * 64 + n] = accP[s][nt][r] + bb[nt] - pd;
                Q16[(size_t)m * 64 + n] = (_Float16)(accQ[s][nt][r] + pd);
            }
        }
}

// ---- K3: per-partition counting sort with inline 98-wide prefix scan ----
__global__ void __launch_bounds__(256) k_fill3s(const int* __restrict__ binned,
                                                const int* __restrict__ pcur,
                                                int* __restrict__ off,
                                                int* __restrict__ sj) {
    __shared__ int bs[128];
    __shared__ int hist[1024];
    __shared__ int tsum[256];
    int p = blockIdx.x, t = threadIdx.x;

    int c = 0;
    if (t < 128) {
        if (t < NPART) c = min(pcur[t] - t * CAP, CAP);
        bs[t] = c;
    }
    __syncthreads();
    for (int o = 1; o < 128; o <<= 1) {
        int a = 0;
        if (t < 128 && t >= o) a = bs[t - o];
        __syncthreads();
        if (t < 128) bs[t] += a;
        __syncthreads();
    }
    int cp = min(pcur[p] - p * CAP, CAP);
    int b0g = bs[p] - cp;
    int cnt_p = cp;
    int total = bs[NPART - 1];
    const int* src = binned + p * CAP;

    #pragma unroll
    for (int q = 0; q < 4; ++q) hist[t * 4 + q] = 0;
    __syncthreads();
    for (int e = t; e < cnt_p; e += 256) atomicAdd(&hist[src[e] >> 17], 1);
    __syncthreads();

    int b0 = hist[t * 4], b1 = hist[t * 4 + 1], b2 = hist[t * 4 + 2], b3 = hist[t * 4 + 3];
    int c1 = b0, c2 = c1 + b1, c3 = c2 + b2, tot = c3 + b3;
    tsum[t] = tot;
    __syncthreads();
    for (int o = 1; o < 256; o <<= 1) {
        int a = (t >= o) ? tsum[t - o] : 0;
        __syncthreads();
        tsum[t] += a;
        __syncthreads();
    }
    int tex = tsum[t] - tot;
    hist[t * 4]     = tex;
    hist[t * 4 + 1] = tex + c1;
    hist[t * 4 + 2] = tex + c2;
    hist[t * 4 + 3] = tex + c3;
    __syncthreads();

    int lo = p * 1024;
    #pragma unroll
    for (int q = 0; q < 4; ++q) {
        int n = t * 4 + q, g = lo + n;
        if (g < N_NODES) off[g] = b0g + hist[n];
    }
    if (p == NPART - 1 && t == 0) off[N_NODES] = total;
    __syncthreads();

    for (int e = t; e < cnt_p; e += 256) {
        int v = src[e];
        int slot = atomicAdd(&hist[v >> 17], 1);
        sj[b0g + slot] = v & 0x1FFFF;
    }
}

// ---- K4: FUSED c1+c2, LDS OVERLAY (hm and lsh share one 16KB buffer) ----
// Wave w's phase-2 reads hm rows [32w,32w+32) only; its lsh region overlays
// exactly those bytes -> no cross-wave hazard after the post-c1 barrier.
#define G1(k) int j##k = __builtin_amdgcn_readlane(jv, G + k); \
              float v##k = (float)Q16[(size_t)j##k * 64 + lane];
#define G2(k) r += (G + k < m) ? fmaxf(Pv + v##k, 0.f) : 0.f;

template<int G>
__device__ __forceinline__ float grp16(int jv, int m, float Pv, int lane,
                                       const _Float16* __restrict__ Q16) {
    if (G >= m) return 0.f;
    G1(0)  G1(1)  G1(2)  G1(3)  G1(4)  G1(5)  G1(6)  G1(7)
    G1(8)  G1(9)  G1(10) G1(11) G1(12) G1(13) G1(14) G1(15)
    float r = 0.f;
    G2(0)  G2(1)  G2(2)  G2(3)  G2(4)  G2(5)  G2(6)  G2(7)
    G2(8)  G2(9)  G2(10) G2(11) G2(12) G2(13) G2(14) G2(15)
    return r;
}

__global__ void __launch_bounds__(256) k_c12(const _Float16* __restrict__ Q16,
                                             const int* __restrict__ off,
                                             const int* __restrict__ sj,
                                             const float* __restrict__ x,
                                             const _Float16* __restrict__ pk,
                                             const float* __restrict__ ab1,
                                             const float* __restrict__ bcomb,
                                             const float* __restrict__ ab2,
                                             float* __restrict__ Pout) {
    __shared__ _Float16 buf[8192];            // hm[128][64] / lsh overlay (16 KB)
    __shared__ unsigned char flags[128];
    int wave = threadIdx.x >> 6, lane = threadIdx.x & 63;
    int m0 = blockIdx.x * 128;

    // ---- c1 phase: 32 nodes per wave -> hm rows (XOR-swizzled) in buf ----
    for (int n = wave; n < 128; n += 4) {
        int node = m0 + n;
        int sw = lane ^ ((n & 7) << 3);
        if (node >= N_NODES) {
            buf[n * 64 + sw] = (_Float16)0.f;
            if (lane == 0) flags[n] = 0;
            continue;
        }
        float Pv = __builtin_nontemporal_load(&Pout[(size_t)node * 64 + lane]);
        int o0 = off[node], o1 = off[node + 1];
        int dg = o1 - o0;
        float acc = 0.f;
        for (int base = o0; base < o1; base += 64) {
            int m = min(64, o1 - base);
            int jv = (lane < m) ? __builtin_nontemporal_load(&sj[base + lane]) : 0;
            acc += grp16<0>(jv, m, Pv, lane, Q16);
            acc += grp16<16>(jv, m, Pv, lane, Q16);
            acc += grp16<32>(jv, m, Pv, lane, Q16);
            acc += grp16<48>(jv, m, Pv, lane, Q16);
        }
        buf[n * 64 + sw] = (_Float16)((dg > 0) ? acc / (float)dg : 0.f);
        if (lane == 0) flags[n] = (dg > 0) ? 1 : 0;
    }
    __syncthreads();

    // ---- c2 phase ----
    int w = wave, l = threadIdx.x & 63;
    int mb = m0 + w * 32;
    int col = l & 15;
    f32x4 z = {0.f, 0.f, 0.f, 0.f};
    f32x4 acc[2][4];
    #pragma unroll
    for (int s = 0; s < 2; ++s)
        #pragma unroll
        for (int nt = 0; nt < 4; ++nt) acc[s][nt] = z;

    {   // phase 1: x @ aw1_top
        half8 a[2][2];
        #pragma unroll
        for (int s = 0; s < 2; ++s)
            #pragma unroll
            for (int kg = 0; kg < 2; ++kg) {
                int row = mb + s * 16 + (l & 15);
                if (row >= N_NODES) row = N_NODES - 1;
                a[s][kg] = afrag_f32(x, row, kg, l);
            }
        const _Float16* pk1 = pk + 2 * 4096;
        #pragma unroll
        for (int nt = 0; nt < 4; ++nt)
            #pragma unroll
            for (int kg = 0; kg < 2; ++kg) {
                half8 b = *(const half8*)(pk1 + ((nt * 2 + kg) * 64 + l) * 8);
                acc[0][nt] = __builtin_amdgcn_mfma_f32_16x16x32_f16(a[0][kg], b, acc[0][nt], 0, 0, 0);
                acc[1][nt] = __builtin_amdgcn_mfma_f32_16x16x32_f16(a[1][kg], b, acc[1][nt], 0, 0, 0);
            }
    }
    {   // phase 2: + hm @ wcomb (A-frags from swizzled buf rows of THIS wave)
        half8 a[2][2];
        #pragma unroll
        for (int s = 0; s < 2; ++s)
            #pragma unroll
            for (int kg = 0; kg < 2; ++kg) {
                int lr = w * 32 + s * 16 + (l & 15);
                int c0 = (kg * 32 + ((l >> 4) << 3)) ^ ((lr & 7) << 3);
                a[s][kg] = *(const half8*)&buf[lr * 64 + c0];
            }
        const _Float16* pk2 = pk + 3 * 4096;
        #pragma unroll
        for (int nt = 0; nt < 4; ++nt)
            #pragma unroll
            for (int kg = 0; kg < 2; ++kg) {
                half8 b = *(const half8*)(pk2 + ((nt * 2 + kg) * 64 + l) * 8);
                acc[0][nt] = __builtin_amdgcn_mfma_f32_16x16x32_f16(a[0][kg], b, acc[0][nt], 0, 0, 0);
                acc[1][nt] = __builtin_amdgcn_mfma_f32_16x16x32_f16(a[1][kg], b, acc[1][nt], 0, 0, 0);
            }
    }

    // bias + relu -> h2 fp16 OVERLAY into the same per-wave region of buf
    float a1n[4], bcn[4];
    #pragma unroll
    for (int nt = 0; nt < 4; ++nt) {
        int n = nt * 16 + col;
        a1n[nt] = ab1[n];
        bcn[nt] = bcomb[n];
    }
    #pragma unroll
    for (int s = 0; s < 2; ++s)
        #pragma unroll
        for (int r = 0; r < 4; ++r) {
            int row = ((l >> 4) << 2) + r;
            int lr = w * 32 + s * 16 + row;
            int fg = flags[lr];
            #pragma unroll
            for (int nt = 0; nt < 4; ++nt) {
                int n = nt * 16 + col;
                float v = acc[s][nt][r] + a1n[nt] + (fg ? bcn[nt] : 0.f);
                v = fmaxf(v, 0.f);
                // lsh[w][s][row][n'] == buf[((w*2+s)*16+row)*64 + n'] — overlays
                // hm rows [32w,32w+32) which only THIS wave read in phase 2.
                buf[((w * 2 + s) * 16 + row) * 64 + (n ^ ((row & 7) << 3))] = (_Float16)v;
            }
        }

    f32x4 acc2[2][4];
    #pragma unroll
    for (int s = 0; s < 2; ++s)
        #pragma unroll
        for (int nt = 0; nt < 4; ++nt) acc2[s][nt] = z;
    {   // phase 3: h2 @ aw2 (reads own wave's overlay region, in-order per wave)
        half8 a[2][2];
        #pragma unroll
        for (int s = 0; s < 2; ++s)
            #pragma unroll
            for (int kg = 0; kg < 2; ++kg) {
                int rr = l & 15;
                int c0 = (kg * 32 + ((l >> 4) << 3)) ^ ((rr & 7) << 3);
                a[s][kg] = *(const half8*)&buf[((w * 2 + s) * 16 + rr) * 64 + c0];
            }
        const _Float16* pk3 = pk + 4 * 4096;
        #pragma unroll
        for (int nt = 0; nt < 4; ++nt)
            #pragma unroll
            for (int kg = 0; kg < 2; ++kg) {
                half8 b = *(const half8*)(pk3 + ((nt * 2 + kg) * 64 + l) * 8);
                acc2[0][nt] = __builtin_amdgcn_mfma_f32_16x16x32_f16(a[0][kg], b, acc2[0][nt], 0, 0, 0);
                acc2[1][nt] = __builtin_amdgcn_mfma_f32_16x16x32_f16(a[1][kg], b, acc2[1][nt], 0, 0, 0);
            }
    }

    float a2n[4];
    #pragma unroll
    for (int nt = 0; nt < 4; ++nt) a2n[nt] = ab2[nt * 16 + col];
    #pragma unroll
    for (int s = 0; s < 2; ++s)
        #pragma unroll
        for (int r = 0; r < 4; ++r) {
            int m = mb + s * 16 + ((l >> 4) << 2) + r;
            if (m >= N_NODES) continue;
            #pragma unroll
            for (int nt = 0; nt < 4; ++nt)
                Pout[(size_t)m * 64 + nt * 16 + col] = acc2[s][nt][r] + a2n[nt];
        }
}

extern "C" void kernel_launch(void* const* d_in, const int* in_sizes, int n_in,
                              void* d_out, int out_size, void* d_ws, size_t ws_size,
                              hipStream_t stream) {
    const float* x   = (const float*)d_in[0];
    const int*   ei  = (const int*)d_in[1];
    const int*   ej  = ((const int*)d_in[1]) + N_EDGES;
    const float* pos = (const float*)d_in[2];
    const float* mw1 = (const float*)d_in[3];
    const float* mb1 = (const float*)d_in[4];
    const float* mw2 = (const float*)d_in[5];
    const float* mb2 = (const float*)d_in[6];
    const float* aw1 = (const float*)d_in[7];
    const float* ab1 = (const float*)d_in[8];
    const float* aw2 = (const float*)d_in[9];
    const float* ab2 = (const float*)d_in[10];

    char* ws = (char*)d_ws;
    int*       off    = (int*)(ws + WS_OFF);
    int*       pcur   = (int*)(ws + WS_PCUR);
    int*       sj     = (int*)(ws + WS_SJ);
    float*     bcomb  = (float*)(ws + WS_BCOMB);
    _Float16*  pk     = (_Float16*)(ws + WS_PK);
    _Float16*  Q16    = (_Float16*)(ws + WS_Q);
    int*       binned = (int*)(ws + WS_BIN);
    float*     out    = (float*)d_out;

    hipLaunchKernelGGL(k_setup,  dim3(6), dim3(256), 0, stream,
                       mw1, mw2, mb2, aw1, aw2, pk, bcomb, pcur);
    hipLaunchKernelGGL(k_binpre, dim3(NBB + NBT), dim3(256), 0, stream,
                       ei, ej, pcur, binned, x, pos, mw1, mb1, pk, out, Q16);
    hipLaunchKernelGGL(k_fill3s, dim3(NPART), dim3(256), 0, stream,
                       binned, pcur, off, sj);
    hipLaunchKernelGGL(k_c12,    dim3(NBT), dim3(256), 0, stream,
                       Q16, off, sj, x, pk, ab1, bcomb, ab2, out);
}

// Round 18
// 164.998 us; speedup vs baseline: 1.1074x; 1.1074x over previous
//
#include <hip/hip_runtime.h>
#include <hip/hip_fp16.h>

#define N_NODES 100000
#define N_EDGES 1600000
#define NPART 98           // partitions of 1024 nodes
#define CAP   20480        // bucket capacity
#define EB    8192         // edges per binc block
#define NBB   ((N_EDGES + EB - 1) / EB)        // 196
#define NBT   ((N_NODES + 127) / 128)          // 782

typedef _Float16 half8 __attribute__((ext_vector_type(8)));
typedef float f32x4 __attribute__((ext_vector_type(4)));

// ---------------- workspace layout (bytes) ----------------
#define WS_OFF   0          // int[N+1]
#define WS_PCUR  400016     // int[128]
#define WS_SJ    401040     // int[E]           (6.4 MB)
#define WS_BCOMB 6817424    // float[64]
#define WS_PK    6817680    // _Float16[5*4096] (40 KB)
#define WS_Q     6858640    // _Float16[N*64]   (12.8 MB)
#define WS_BIN   19658640   // int[NPART*CAP]   (8.0 MB)
#define WS_HM16  19658640   // _Float16[N*64]   overlays BIN (disjoint lifetimes)

// ---- K1: weight packing (wcomb inline) + bcomb + pcur init ----
__global__ void __launch_bounds__(256) k_setup(const float* __restrict__ mw1,
                                               const float* __restrict__ mw2,
                                               const float* __restrict__ mb2,
                                               const float* __restrict__ aw1,
                                               const float* __restrict__ aw2,
                                               _Float16* __restrict__ pk,
                                               float* __restrict__ bcomb,
                                               int* __restrict__ pcur) {
    __shared__ float wc[4096];
    int blk = blockIdx.x, t = threadIdx.x;
    if (blk < 5) {
        const float* src;
        if (blk == 3) {
            for (int o = t; o < 4096; o += 256) {
                int c = o >> 6, k = o & 63;
                float s = 0.f;
                #pragma unroll 8
                for (int a = 0; a < 64; ++a) s += mw2[c * 64 + a] * aw1[(64 + a) * 64 + k];
                wc[o] = s;
            }
            __syncthreads();
            src = wc;
        } else {
            src = (blk == 0) ? mw1 : (blk == 1) ? (mw1 + 4096)
                : (blk == 2) ? aw1 : aw2;
        }
        _Float16* dst = pk + blk * 4096;
        for (int o = t; o < 4096; o += 256) {
            int b_ = o & 7, l = (o >> 3) & 63, z = o >> 9;
            int kg = z & 1, nt = z >> 1;
            int k = kg * 32 + ((l >> 4) << 3) + b_;
            int n = nt * 16 + (l & 15);
            dst[o] = (_Float16)src[k * 64 + n];
        }
    } else {
        if (t < 64) {
            float s = 0.f;
            #pragma unroll 8
            for (int a = 0; a < 64; ++a) s += mb2[a] * aw1[(64 + a) * 64 + t];
            bcomb[t] = s;
        }
        if (t < 128) pcur[t] = t * CAP;
    }
}

// ---- MFMA helpers ----
__device__ __forceinline__ half8 afrag_f32(const float* src, int row, int kg, int l) {
    const float* p = src + (size_t)row * 64 + kg * 32 + ((l >> 4) << 3);
    float4 u = *(const float4*)p;
    float4 v = *(const float4*)(p + 4);
    half8 h;
    h[0] = (_Float16)u.x; h[1] = (_Float16)u.y; h[2] = (_Float16)u.z; h[3] = (_Float16)u.w;
    h[4] = (_Float16)v.x; h[5] = (_Float16)v.y; h[6] = (_Float16)v.z; h[7] = (_Float16)v.w;
    return h;
}

// ---- K2: binc (blocks 0..NBB-1)  ||  pre (blocks NBB..NBB+NBT-1) ----
__global__ void __launch_bounds__(256) k_binpre(const int* __restrict__ ei,
                                                const int* __restrict__ ej,
                                                int* pcur, int* __restrict__ binned,
                                                const float* __restrict__ x,
                                                const float* __restrict__ pos,
                                                const float* __restrict__ mw1,
                                                const float* __restrict__ mb1,
                                                const _Float16* __restrict__ pk,
                                                float* __restrict__ P,
                                                _Float16* __restrict__ Q16) {
    __shared__ int cnt[NPART];
    __shared__ int wcur[NPART];
    int t = threadIdx.x;
    if (blockIdx.x < NBB) {
        for (int q = t; q < NPART; q += 256) cnt[q] = 0;
        __syncthreads();
        int base_e = blockIdx.x * EB;
        #pragma unroll 2
        for (int it = 0; it < EB / 1024; ++it) {
            int e = base_e + it * 1024 + t * 4;
            if (e < N_EDGES) {
                int4 iv = *(const int4*)(ei + e);
                atomicAdd(&cnt[iv.x >> 10], 1);
                atomicAdd(&cnt[iv.y >> 10], 1);
                atomicAdd(&cnt[iv.z >> 10], 1);
                atomicAdd(&cnt[iv.w >> 10], 1);
            }
        }
        __syncthreads();
        for (int q = t; q < NPART; q += 256)
            wcur[q] = cnt[q] ? atomicAdd(&pcur[q], cnt[q]) : 0;
        __syncthreads();
        #pragma unroll 2
        for (int it = 0; it < EB / 1024; ++it) {
            int e = base_e + it * 1024 + t * 4;
            if (e < N_EDGES) {
                int4 iv = *(const int4*)(ei + e);
                int4 jv = *(const int4*)(ej + e);
                int a, p;
                p = iv.x >> 10; a = atomicAdd(&wcur[p], 1);
                if (a < (p + 1) * CAP) binned[a] = ((iv.x & 1023) << 17) | jv.x;
                p = iv.y >> 10; a = atomicAdd(&wcur[p], 1);
                if (a < (p + 1) * CAP) binned[a] = ((iv.y & 1023) << 17) | jv.y;
                p = iv.z >> 10; a = atomicAdd(&wcur[p], 1);
                if (a < (p + 1) * CAP) binned[a] = ((iv.z & 1023) << 17) | jv.z;
                p = iv.w >> 10; a = atomicAdd(&wcur[p], 1);
                if (a < (p + 1) * CAP) binned[a] = ((iv.w & 1023) << 17) | jv.w;
            }
        }
        return;
    }
    // ---- pre: P' = x@W1a + mb1 - pos@W1p (fp32); Q' = x@W1b + pos@W1p (fp16) ----
    int bid = blockIdx.x - NBB;
    int w = t >> 6, l = t & 63;
    int m0 = bid * 128 + w * 32;

    half8 a[2][2];
    #pragma unroll
    for (int s = 0; s < 2; ++s)
        #pragma unroll
        for (int kg = 0; kg < 2; ++kg) {
            int row = m0 + s * 16 + (l & 15);
            if (row >= N_NODES) row = N_NODES - 1;
            a[s][kg] = afrag_f32(x, row, kg, l);
        }

    f32x4 z = {0.f, 0.f, 0.f, 0.f};
    f32x4 accP[2][4], accQ[2][4];
    #pragma unroll
    for (int s = 0; s < 2; ++s)
        #pragma unroll
        for (int nt = 0; nt < 4; ++nt) { accP[s][nt] = z; accQ[s][nt] = z; }

    #pragma unroll
    for (int nt = 0; nt < 4; ++nt)
        #pragma unroll
        for (int kg = 0; kg < 2; ++kg) {
            half8 b = *(const half8*)(pk + ((nt * 2 + kg) * 64 + l) * 8);
            accP[0][nt] = __builtin_amdgcn_mfma_f32_16x16x32_f16(a[0][kg], b, accP[0][nt], 0, 0, 0);
            accP[1][nt] = __builtin_amdgcn_mfma_f32_16x16x32_f16(a[1][kg], b, accP[1][nt], 0, 0, 0);
        }
    const _Float16* pkb = pk + 4096;
    #pragma unroll
    for (int nt = 0; nt < 4; ++nt)
        #pragma unroll
        for (int kg = 0; kg < 2; ++kg) {
            half8 b = *(const half8*)(pkb + ((nt * 2 + kg) * 64 + l) * 8);
            accQ[0][nt] = __builtin_amdgcn_mfma_f32_16x16x32_f16(a[0][kg], b, accQ[0][nt], 0, 0, 0);
            accQ[1][nt] = __builtin_amdgcn_mfma_f32_16x16x32_f16(a[1][kg], b, accQ[1][nt], 0, 0, 0);
        }

    int col = l & 15;
    float wx[4], wy[4], wz[4], bb[4];
    #pragma unroll
    for (int nt = 0; nt < 4; ++nt) {
        int n = nt * 16 + col;
        wx[nt] = mw1[128 * 64 + n];
        wy[nt] = mw1[129 * 64 + n];
        wz[nt] = mw1[130 * 64 + n];
        bb[nt] = mb1[n];
    }
    #pragma unroll
    for (int s = 0; s < 2; ++s)
        #pragma unroll
        for (int r = 0; r < 4; ++r) {
            int m = m0 + s * 16 + ((l >> 4) << 2) + r;
            if (m >= N_NODES) continue;
            float px = pos[3 * m], py = pos[3 * m + 1], pz = pos[3 * m + 2];
            #pragma unroll
            for (int nt = 0; nt < 4; ++nt) {
                int n = nt * 16 + col;
                float pd = px * wx[nt] + py * wy[nt] + pz * wz[nt];
                __builtin_nontemporal_store(accP[s][nt][r] + bb[nt] - pd,
                                            &P[(size_t)m * 64 + n]);
                __builtin_nontemporal_store((_Float16)(accQ[s][nt][r] + pd),
                                            &Q16[(size_t)m * 64 + n]);
            }
        }
}

// ---- K3: per-partition counting sort with inline 98-wide prefix scan ----
__global__ void __launch_bounds__(256) k_fill3s(const int* __restrict__ binned,
                                                const int* __restrict__ pcur,
                                                int* __restrict__ off,
                                                int* __restrict__ sj) {
    __shared__ int bs[128];
    __shared__ int hist[1024];
    __shared__ int tsum[256];
    int p = blockIdx.x, t = threadIdx.x;

    int c = 0;
    if (t < 128) {
        if (t < NPART) c = min(pcur[t] - t * CAP, CAP);
        bs[t] = c;
    }
    __syncthreads();
    for (int o = 1; o < 128; o <<= 1) {
        int a = 0;
        if (t < 128 && t >= o) a = bs[t - o];
        __syncthreads();
        if (t < 128) bs[t] += a;
        __syncthreads();
    }
    int cp = min(pcur[p] - p * CAP, CAP);
    int b0g = bs[p] - cp;
    int cnt_p = cp;
    int total = bs[NPART - 1];
    const int* src = binned + p * CAP;

    #pragma unroll
    for (int q = 0; q < 4; ++q) hist[t * 4 + q] = 0;
    __syncthreads();
    for (int e = t; e < cnt_p; e += 256) atomicAdd(&hist[src[e] >> 17], 1);
    __syncthreads();

    int b0 = hist[t * 4], b1 = hist[t * 4 + 1], b2 = hist[t * 4 + 2], b3 = hist[t * 4 + 3];
    int c1 = b0, c2 = c1 + b1, c3 = c2 + b2, tot = c3 + b3;
    tsum[t] = tot;
    __syncthreads();
    for (int o = 1; o < 256; o <<= 1) {
        int a = (t >= o) ? tsum[t - o] : 0;
        __syncthreads();
        tsum[t] += a;
        __syncthreads();
    }
    int tex = tsum[t] - tot;
    hist[t * 4]     = tex;
    hist[t * 4 + 1] = tex + c1;
    hist[t * 4 + 2] = tex + c2;
    hist[t * 4 + 3] = tex + c3;
    __syncthreads();

    int lo = p * 1024;
    #pragma unroll
    for (int q = 0; q < 4; ++q) {
        int n = t * 4 + q, g = lo + n;
        if (g < N_NODES) off[g] = b0g + hist[n];
    }
    if (p == NPART - 1 && t == 0) off[N_NODES] = total;
    __syncthreads();

    for (int e = t; e < cnt_p; e += 256) {
        int v = src[e];
        int slot = atomicAdd(&hist[v >> 17], 1);
        sj[b0g + slot] = v & 0x1FFFF;
    }
}

// ---- K4: edge aggregation, fp16 Q, named-register 16-deep gather groups ----
#define G1(k) int j##k = __builtin_amdgcn_readlane(jv, G + k); \
              float v##k = (float)Q16[(size_t)j##k * 64 + lane];
#define G2(k) r += (G + k < m) ? fmaxf(Pv + v##k, 0.f) : 0.f;

template<int G>
__device__ __forceinline__ float grp16(int jv, int m, float Pv, int lane,
                                       const _Float16* __restrict__ Q16) {
    if (G >= m) return 0.f;
    G1(0)  G1(1)  G1(2)  G1(3)  G1(4)  G1(5)  G1(6)  G1(7)
    G1(8)  G1(9)  G1(10) G1(11) G1(12) G1(13) G1(14) G1(15)
    float r = 0.f;
    G2(0)  G2(1)  G2(2)  G2(3)  G2(4)  G2(5)  G2(6)  G2(7)
    G2(8)  G2(9)  G2(10) G2(11) G2(12) G2(13) G2(14) G2(15)
    return r;
}

__global__ void __launch_bounds__(256) k_c1(const _Float16* __restrict__ Q16,
                                            const int* __restrict__ off,
                                            const int* __restrict__ sj,
                                            const float* __restrict__ Phm,
                                            _Float16* __restrict__ hm16) {
    int wave = threadIdx.x >> 6, lane = threadIdx.x & 63;
    int node = blockIdx.x * 4 + wave;
    if (node >= N_NODES) return;
    float Pv = __builtin_nontemporal_load(&Phm[(size_t)node * 64 + lane]);
    int o0 = off[node], o1 = off[node + 1];
    int dg = o1 - o0;
    float acc = 0.f;
    for (int base = o0; base < o1; base += 64) {
        int m = min(64, o1 - base);
        int jv = (lane < m) ? __builtin_nontemporal_load(&sj[base + lane]) : 0;
        acc += grp16<0>(jv, m, Pv, lane, Q16);
        acc += grp16<16>(jv, m, Pv, lane, Q16);
        acc += grp16<32>(jv, m, Pv, lane, Q16);
        acc += grp16<48>(jv, m, Pv, lane, Q16);
    }
    _Float16 hv = (_Float16)((dg > 0) ? acc / (float)dg : 0.f);
    __builtin_nontemporal_store(hv, &hm16[(size_t)node * 64 + lane]);
}

// ---- K5: out = relu(x@aw1t + hm@wcomb + ab1 + [deg>0]*bcomb) @ aw2 + ab2 ----
__global__ void __launch_bounds__(256) k_c2(const float* __restrict__ x,
                                            const _Float16* __restrict__ hm16,
                                            const _Float16* __restrict__ pk,
                                            const float* __restrict__ ab1,
                                            const float* __restrict__ bcomb,
                                            const float* __restrict__ ab2,
                                            const int* __restrict__ off,
                                            float* __restrict__ out) {
    __shared__ _Float16 lsh[4][2][16][64];
    int w = threadIdx.x >> 6, l = threadIdx.x & 63;
    int m0 = blockIdx.x * 128 + w * 32;
    int col = l & 15;

    f32x4 z = {0.f, 0.f, 0.f, 0.f};
    f32x4 acc[2][4];
    #pragma unroll
    for (int s = 0; s < 2; ++s)
        #pragma unroll
        for (int nt = 0; nt < 4; ++nt) acc[s][nt] = z;

    {
        half8 a[2][2];
        #pragma unroll
        for (int s = 0; s < 2; ++s)
            #pragma unroll
            for (int kg = 0; kg < 2; ++kg) {
                int row = m0 + s * 16 + (l & 15);
                if (row >= N_NODES) row = N_NODES - 1;
                a[s][kg] = afrag_f32(x, row, kg, l);
            }
        const _Float16* pk1 = pk + 2 * 4096;
        #pragma unroll
        for (int nt = 0; nt < 4; ++nt)
            #pragma unroll
            for (int kg = 0; kg < 2; ++kg) {
                half8 b = *(const half8*)(pk1 + ((nt * 2 + kg) * 64 + l) * 8);
                acc[0][nt] = __builtin_amdgcn_mfma_f32_16x16x32_f16(a[0][kg], b, acc[0][nt], 0, 0, 0);
                acc[1][nt] = __builtin_amdgcn_mfma_f32_16x16x32_f16(a[1][kg], b, acc[1][nt], 0, 0, 0);
            }
    }
    {
        half8 a[2][2];
        #pragma unroll
        for (int s = 0; s < 2; ++s)
            #pragma unroll
            for (int kg = 0; kg < 2; ++kg) {
                int row = m0 + s * 16 + (l & 15);
                if (row >= N_NODES) row = N_NODES - 1;
                a[s][kg] = *(const half8*)(hm16 + (size_t)row * 64 + kg * 32 + ((l >> 4) << 3));
            }
        const _Float16* pk2 = pk + 3 * 4096;
        #pragma unroll
        for (int nt = 0; nt < 4; ++nt)
            #pragma unroll
            for (int kg = 0; kg < 2; ++kg) {
                half8 b = *(const half8*)(pk2 + ((nt * 2 + kg) * 64 + l) * 8);
                acc[0][nt] = __builtin_amdgcn_mfma_f32_16x16x32_f16(a[0][kg], b, acc[0][nt], 0, 0, 0);
                acc[1][nt] = __builtin_amdgcn_mfma_f32_16x16x32_f16(a[1][kg], b, acc[1][nt], 0, 0, 0);
            }
    }

    float a1n[4], bcn[4];
    #pragma unroll
    for (int nt = 0; nt < 4; ++nt) {
        int n = nt * 16 + col;
        a1n[nt] = ab1[n];
        bcn[nt] = bcomb[n];
    }
    #pragma unroll
    for (int s = 0; s < 2; ++s)
        #pragma unroll
        for (int r = 0; r < 4; ++r) {
            int row = ((l >> 4) << 2) + r;
            int m = m0 + s * 16 + row;
            int dg = (m < N_NODES) ? (off[m + 1] - off[m]) : 0;
            #pragma unroll
            for (int nt = 0; nt < 4; ++nt) {
                int n = nt * 16 + col;
                float v = acc[s][nt][r] + a1n[nt] + ((dg > 0) ? bcn[nt] : 0.f);
                v = fmaxf(v, 0.f);
                lsh[w][s][row][n ^ ((row & 7) << 3)] = (_Float16)v;
            }
        }
    __syncthreads();

    f32x4 acc2[2][4];
    #pragma unroll
    for (int s = 0; s < 2; ++s)
        #pragma unroll
        for (int nt = 0; nt < 4; ++nt) acc2[s][nt] = z;
    {
        half8 a[2][2];
        #pragma unroll
        for (int s = 0; s < 2; ++s)
            #pragma unroll
            for (int kg = 0; kg < 2; ++kg) {
                int rr = l & 15;
                int c0 = (kg * 32 + ((l >> 4) << 3)) ^ ((rr & 7) << 3);
                a[s][kg] = *(const half8*)&lsh[w][s][rr][c0];
            }
        const _Float16* pk3 = pk + 4 * 4096;
        #pragma unroll
        for (int nt = 0; nt < 4; ++nt)
            #pragma unroll
            for (int kg = 0; kg < 2; ++kg) {
                half8 b = *(const half8*)(pk3 + ((nt * 2 + kg) * 64 + l) * 8);
                acc2[0][nt] = __builtin_amdgcn_mfma_f32_16x16x32_f16(a[0][kg], b, acc2[0][nt], 0, 0, 0);
                acc2[1][nt] = __builtin_amdgcn_mfma_f32_16x16x32_f16(a[1][kg], b, acc2[1][nt], 0, 0, 0);
            }
    }

    float a2n[4];
    #pragma unroll
    for (int nt = 0; nt < 4; ++nt) a2n[nt] = ab2[nt * 16 + col];
    #pragma unroll
    for (int s = 0; s < 2; ++s)
        #pragma unroll
        for (int r = 0; r < 4; ++r) {
            int m = m0 + s * 16 + ((l >> 4) << 2) + r;
            if (m >= N_NODES) continue;
            #pragma unroll
            for (int nt = 0; nt < 4; ++nt)
                out[(size_t)m * 64 + nt * 16 + col] = acc2[s][nt][r] + a2n[nt];
        }
}

extern "C" void kernel_launch(void* const* d_in, const int* in_sizes, int n_in,
                              void* d_out, int out_size, void* d_ws, size_t ws_size,
                              hipStream_t stream) {
    const float* x   = (const float*)d_in[0];
    const int*   ei  = (const int*)d_in[1];
    const int*   ej  = ((const int*)d_in[1]) + N_EDGES;
    const float* pos = (const float*)d_in[2];
    const float* mw1 = (const float*)d_in[3];
    const float* mb1 = (const float*)d_in[4];
    const float* mw2 = (const float*)d_in[5];
    const float* mb2 = (const float*)d_in[6];
    const float* aw1 = (const float*)d_in[7];
    const float* ab1 = (const float*)d_in[8];
    const float* aw2 = (const float*)d_in[9];
    const float* ab2 = (const float*)d_in[10];

    char* ws = (char*)d_ws;
    int*       off    = (int*)(ws + WS_OFF);
    int*       pcur   = (int*)(ws + WS_PCUR);
    int*       sj     = (int*)(ws + WS_SJ);
    float*     bcomb  = (float*)(ws + WS_BCOMB);
    _Float16*  pk     = (_Float16*)(ws + WS_PK);
    _Float16*  Q16    = (_Float16*)(ws + WS_Q);
    int*       binned = (int*)(ws + WS_BIN);
    _Float16*  hm16   = (_Float16*)(ws + WS_HM16);
    float*     out    = (float*)d_out;

    hipLaunchKernelGGL(k_setup,  dim3(6), dim3(256), 0, stream,
                       mw1, mw2, mb2, aw1, aw2, pk, bcomb, pcur);
    hipLaunchKernelGGL(k_binpre, dim3(NBB + NBT), dim3(256), 0, stream,
                       ei, ej, pcur, binned, x, pos, mw1, mb1, pk, out, Q16);
    hipLaunchKernelGGL(k_fill3s, dim3(NPART), dim3(256), 0, stream,
                       binned, pcur, off, sj);
    hipLaunchKernelGGL(k_c1,     dim3((N_NODES + 3) / 4), dim3(256), 0, stream,
                       Q16, off, sj, out, hm16);
    hipLaunchKernelGGL(k_c2,     dim3(NBT), dim3(256), 0, stream,
                       x, hm16, pk, ab1, bcomb, ab2, off, out);
}

// Round 19
// 163.892 us; speedup vs baseline: 1.1149x; 1.0068x over previous
//
#include <hip/hip_runtime.h>
#include <hip/hip_fp16.h>

#define N_NODES 100000
#define N_EDGES 1600000
#define NPART 98           // partitions of 1024 nodes
#define CAP   20480        // bucket capacity
#define EB    8192         // edges per binc block
#define NBB   ((N_EDGES + EB - 1) / EB)        // 196
#define NBT   ((N_NODES + 127) / 128)          // 782

typedef _Float16 half8 __attribute__((ext_vector_type(8)));
typedef float f32x4 __attribute__((ext_vector_type(4)));

// ---------------- workspace layout (bytes) ----------------
// P16 lives in d_out[0 .. 12.8MB) as scratch; k_c2 overwrites all of d_out.
#define WS_OFF   0          // int[N+1]
#define WS_PCUR  400016     // int[128]
#define WS_SJ    401040     // int[E]           (6.4 MB)
#define WS_BCOMB 6817424    // float[64]
#define WS_PK    6817680    // _Float16[5*4096] (40 KB)
#define WS_Q     6858640    // _Float16[N*64]   (12.8 MB)
#define WS_BIN   19658640   // int[NPART*CAP]   (8.0 MB)
#define WS_HM16  19658640   // _Float16[N*64]   overlays BIN (disjoint lifetimes)

// ---- K1: weight packing (wcomb inline) + bcomb + pcur init ----
__global__ void __launch_bounds__(256) k_setup(const float* __restrict__ mw1,
                                               const float* __restrict__ mw2,
                                               const float* __restrict__ mb2,
                                               const float* __restrict__ aw1,
                                               const float* __restrict__ aw2,
                                               _Float16* __restrict__ pk,
                                               float* __restrict__ bcomb,
                                               int* __restrict__ pcur) {
    __shared__ float wc[4096];
    int blk = blockIdx.x, t = threadIdx.x;
    if (blk < 5) {
        const float* src;
        if (blk == 3) {
            for (int o = t; o < 4096; o += 256) {
                int c = o >> 6, k = o & 63;
                float s = 0.f;
                #pragma unroll 8
                for (int a = 0; a < 64; ++a) s += mw2[c * 64 + a] * aw1[(64 + a) * 64 + k];
                wc[o] = s;
            }
            __syncthreads();
            src = wc;
        } else {
            src = (blk == 0) ? mw1 : (blk == 1) ? (mw1 + 4096)
                : (blk == 2) ? aw1 : aw2;
        }
        _Float16* dst = pk + blk * 4096;
        for (int o = t; o < 4096; o += 256) {
            int b_ = o & 7, l = (o >> 3) & 63, z = o >> 9;
            int kg = z & 1, nt = z >> 1;
            int k = kg * 32 + ((l >> 4) << 3) + b_;
            int n = nt * 16 + (l & 15);
            dst[o] = (_Float16)src[k * 64 + n];
        }
    } else {
        if (t < 64) {
            float s = 0.f;
            #pragma unroll 8
            for (int a = 0; a < 64; ++a) s += mb2[a] * aw1[(64 + a) * 64 + t];
            bcomb[t] = s;
        }
        if (t < 128) pcur[t] = t * CAP;
    }
}

// ---- MFMA helpers ----
__device__ __forceinline__ half8 afrag_f32(const float* src, int row, int kg, int l) {
    const float* p = src + (size_t)row * 64 + kg * 32 + ((l >> 4) << 3);
    float4 u = *(const float4*)p;
    float4 v = *(const float4*)(p + 4);
    half8 h;
    h[0] = (_Float16)u.x; h[1] = (_Float16)u.y; h[2] = (_Float16)u.z; h[3] = (_Float16)u.w;
    h[4] = (_Float16)v.x; h[5] = (_Float16)v.y; h[6] = (_Float16)v.z; h[7] = (_Float16)v.w;
    return h;
}

// ---- K2: binc (blocks 0..NBB-1)  ||  pre (blocks NBB..NBB+NBT-1) ----
__global__ void __launch_bounds__(256) k_binpre(const int* __restrict__ ei,
                                                const int* __restrict__ ej,
                                                int* pcur, int* __restrict__ binned,
                                                const float* __restrict__ x,
                                                const float* __restrict__ pos,
                                                const float* __restrict__ mw1,
                                                const float* __restrict__ mb1,
                                                const _Float16* __restrict__ pk,
                                                _Float16* __restrict__ P16,
                                                _Float16* __restrict__ Q16) {
    __shared__ int cnt[NPART];
    __shared__ int wcur[NPART];
    int t = threadIdx.x;
    if (blockIdx.x < NBB) {
        for (int q = t; q < NPART; q += 256) cnt[q] = 0;
        __syncthreads();
        int base_e = blockIdx.x * EB;
        #pragma unroll 2
        for (int it = 0; it < EB / 1024; ++it) {
            int e = base_e + it * 1024 + t * 4;
            if (e < N_EDGES) {
                int4 iv = *(const int4*)(ei + e);
                atomicAdd(&cnt[iv.x >> 10], 1);
                atomicAdd(&cnt[iv.y >> 10], 1);
                atomicAdd(&cnt[iv.z >> 10], 1);
                atomicAdd(&cnt[iv.w >> 10], 1);
            }
        }
        __syncthreads();
        for (int q = t; q < NPART; q += 256)
            wcur[q] = cnt[q] ? atomicAdd(&pcur[q], cnt[q]) : 0;
        __syncthreads();
        #pragma unroll 2
        for (int it = 0; it < EB / 1024; ++it) {
            int e = base_e + it * 1024 + t * 4;
            if (e < N_EDGES) {
                int4 iv = *(const int4*)(ei + e);
                int4 jv = *(const int4*)(ej + e);
                int a, p;
                p = iv.x >> 10; a = atomicAdd(&wcur[p], 1);
                if (a < (p + 1) * CAP) binned[a] = ((iv.x & 1023) << 17) | jv.x;
                p = iv.y >> 10; a = atomicAdd(&wcur[p], 1);
                if (a < (p + 1) * CAP) binned[a] = ((iv.y & 1023) << 17) | jv.y;
                p = iv.z >> 10; a = atomicAdd(&wcur[p], 1);
                if (a < (p + 1) * CAP) binned[a] = ((iv.z & 1023) << 17) | jv.z;
                p = iv.w >> 10; a = atomicAdd(&wcur[p], 1);
                if (a < (p + 1) * CAP) binned[a] = ((iv.w & 1023) << 17) | jv.w;
            }
        }
        return;
    }
    // ---- pre: P16 = x@W1a + mb1 - pos@W1p (fp16); Q16 = x@W1b + pos@W1p (fp16) ----
    int bid = blockIdx.x - NBB;
    int w = t >> 6, l = t & 63;
    int m0 = bid * 128 + w * 32;

    half8 a[2][2];
    #pragma unroll
    for (int s = 0; s < 2; ++s)
        #pragma unroll
        for (int kg = 0; kg < 2; ++kg) {
            int row = m0 + s * 16 + (l & 15);
            if (row >= N_NODES) row = N_NODES - 1;
            a[s][kg] = afrag_f32(x, row, kg, l);
        }

    f32x4 z = {0.f, 0.f, 0.f, 0.f};
    f32x4 accP[2][4], accQ[2][4];
    #pragma unroll
    for (int s = 0; s < 2; ++s)
        #pragma unroll
        for (int nt = 0; nt < 4; ++nt) { accP[s][nt] = z; accQ[s][nt] = z; }

    #pragma unroll
    for (int nt = 0; nt < 4; ++nt)
        #pragma unroll
        for (int kg = 0; kg < 2; ++kg) {
            half8 b = *(const half8*)(pk + ((nt * 2 + kg) * 64 + l) * 8);
            accP[0][nt] = __builtin_amdgcn_mfma_f32_16x16x32_f16(a[0][kg], b, accP[0][nt], 0, 0, 0);
            accP[1][nt] = __builtin_amdgcn_mfma_f32_16x16x32_f16(a[1][kg], b, accP[1][nt], 0, 0, 0);
        }
    const _Float16* pkb = pk + 4096;
    #pragma unroll
    for (int nt = 0; nt < 4; ++nt)
        #pragma unroll
        for (int kg = 0; kg < 2; ++kg) {
            half8 b = *(const half8*)(pkb + ((nt * 2 + kg) * 64 + l) * 8);
            accQ[0][nt] = __builtin_amdgcn_mfma_f32_16x16x32_f16(a[0][kg], b, accQ[0][nt], 0, 0, 0);
            accQ[1][nt] = __builtin_amdgcn_mfma_f32_16x16x32_f16(a[1][kg], b, accQ[1][nt], 0, 0, 0);
        }

    int col = l & 15;
    float wx[4], wy[4], wz[4], bb[4];
    #pragma unroll
    for (int nt = 0; nt < 4; ++nt) {
        int n = nt * 16 + col;
        wx[nt] = mw1[128 * 64 + n];
        wy[nt] = mw1[129 * 64 + n];
        wz[nt] = mw1[130 * 64 + n];
        bb[nt] = mb1[n];
    }
    #pragma unroll
    for (int s = 0; s < 2; ++s)
        #pragma unroll
        for (int r = 0; r < 4; ++r) {
            int m = m0 + s * 16 + ((l >> 4) << 2) + r;
            if (m >= N_NODES) continue;
            float px = pos[3 * m], py = pos[3 * m + 1], pz = pos[3 * m + 2];
            #pragma unroll
            for (int nt = 0; nt < 4; ++nt) {
                int n = nt * 16 + col;
                float pd = px * wx[nt] + py * wy[nt] + pz * wz[nt];
                __builtin_nontemporal_store((_Float16)(accP[s][nt][r] + bb[nt] - pd),
                                            &P16[(size_t)m * 64 + n]);
                __builtin_nontemporal_store((_Float16)(accQ[s][nt][r] + pd),
                                            &Q16[(size_t)m * 64 + n]);
            }
        }
}

// ---- K3: per-partition counting sort with inline 98-wide prefix scan ----
__global__ void __launch_bounds__(256) k_fill3s(const int* __restrict__ binned,
                                                const int* __restrict__ pcur,
                                                int* __restrict__ off,
                                                int* __restrict__ sj) {
    __shared__ int bs[128];
    __shared__ int hist[1024];
    __shared__ int tsum[256];
    int p = blockIdx.x, t = threadIdx.x;

    int c = 0;
    if (t < 128) {
        if (t < NPART) c = min(pcur[t] - t * CAP, CAP);
        bs[t] = c;
    }
    __syncthreads();
    for (int o = 1; o < 128; o <<= 1) {
        int a = 0;
        if (t < 128 && t >= o) a = bs[t - o];
        __syncthreads();
        if (t < 128) bs[t] += a;
        __syncthreads();
    }
    int cp = min(pcur[p] - p * CAP, CAP);
    int b0g = bs[p] - cp;
    int cnt_p = cp;
    int total = bs[NPART - 1];
    const int* src = binned + p * CAP;

    #pragma unroll
    for (int q = 0; q < 4; ++q) hist[t * 4 + q] = 0;
    __syncthreads();
    for (int e = t; e < cnt_p; e += 256) atomicAdd(&hist[src[e] >> 17], 1);
    __syncthreads();

    int b0 = hist[t * 4], b1 = hist[t * 4 + 1], b2 = hist[t * 4 + 2], b3 = hist[t * 4 + 3];
    int c1 = b0, c2 = c1 + b1, c3 = c2 + b2, tot = c3 + b3;
    tsum[t] = tot;
    __syncthreads();
    for (int o = 1; o < 256; o <<= 1) {
        int a = (t >= o) ? tsum[t - o] : 0;
        __syncthreads();
        tsum[t] += a;
        __syncthreads();
    }
    int tex = tsum[t] - tot;
    hist[t * 4]     = tex;
    hist[t * 4 + 1] = tex + c1;
    hist[t * 4 + 2] = tex + c2;
    hist[t * 4 + 3] = tex + c3;
    __syncthreads();

    int lo = p * 1024;
    #pragma unroll
    for (int q = 0; q < 4; ++q) {
        int n = t * 4 + q, g = lo + n;
        if (g < N_NODES) off[g] = b0g + hist[n];
    }
    if (p == NPART - 1 && t == 0) off[N_NODES] = total;
    __syncthreads();

    for (int e = t; e < cnt_p; e += 256) {
        int v = src[e];
        int slot = atomicAdd(&hist[v >> 17], 1);
        sj[b0g + slot] = v & 0x1FFFF;
    }
}

// ---- K4: edge aggregation, fp16 P/Q, named-register 16-deep gather groups ----
#define G1(k) int j##k = __builtin_amdgcn_readlane(jv, G + k); \
              float v##k = (float)Q16[(size_t)j##k * 64 + lane];
#define G2(k) r += (G + k < m) ? fmaxf(Pv + v##k, 0.f) : 0.f;

template<int G>
__device__ __forceinline__ float grp16(int jv, int m, float Pv, int lane,
                                       const _Float16* __restrict__ Q16) {
    if (G >= m) return 0.f;
    G1(0)  G1(1)  G1(2)  G1(3)  G1(4)  G1(5)  G1(6)  G1(7)
    G1(8)  G1(9)  G1(10) G1(11) G1(12) G1(13) G1(14) G1(15)
    float r = 0.f;
    G2(0)  G2(1)  G2(2)  G2(3)  G2(4)  G2(5)  G2(6)  G2(7)
    G2(8)  G2(9)  G2(10) G2(11) G2(12) G2(13) G2(14) G2(15)
    return r;
}

// 128-thread blocks (2 independent waves) for finer scheduling granularity.
__global__ void __launch_bounds__(128) k_c1(const _Float16* __restrict__ Q16,
                                            const int* __restrict__ off,
                                            const int* __restrict__ sj,
                                            const _Float16* __restrict__ P16,
                                            _Float16* __restrict__ hm16) {
    int wave = threadIdx.x >> 6, lane = threadIdx.x & 63;
    int node = blockIdx.x * 2 + wave;
    if (node >= N_NODES) return;
    float Pv = (float)__builtin_nontemporal_load(&P16[(size_t)node * 64 + lane]);
    int o0 = off[node], o1 = off[node + 1];
    int dg = o1 - o0;
    float acc = 0.f;
    for (int base = o0; base < o1; base += 64) {
        int m = min(64, o1 - base);
        int jv = (lane < m) ? __builtin_nontemporal_load(&sj[base + lane]) : 0;
        acc += grp16<0>(jv, m, Pv, lane, Q16);
        acc += grp16<16>(jv, m, Pv, lane, Q16);
        acc += grp16<32>(jv, m, Pv, lane, Q16);
        acc += grp16<48>(jv, m, Pv, lane, Q16);
    }
    _Float16 hv = (_Float16)((dg > 0) ? acc / (float)dg : 0.f);
    __builtin_nontemporal_store(hv, &hm16[(size_t)node * 64 + lane]);
}

// ---- K5: out = relu(x@aw1t + hm@wcomb + ab1 + [deg>0]*bcomb) @ aw2 + ab2 ----
__global__ void __launch_bounds__(256) k_c2(const float* __restrict__ x,
                                            const _Float16* __restrict__ hm16,
                                            const _Float16* __restrict__ pk,
                                            const float* __restrict__ ab1,
                                            const float* __restrict__ bcomb,
                                            const float* __restrict__ ab2,
                                            const int* __restrict__ off,
                                            float* __restrict__ out) {
    __shared__ _Float16 lsh[4][2][16][64];
    int w = threadIdx.x >> 6, l = threadIdx.x & 63;
    int m0 = blockIdx.x * 128 + w * 32;
    int col = l & 15;

    f32x4 z = {0.f, 0.f, 0.f, 0.f};
    f32x4 acc[2][4];
    #pragma unroll
    for (int s = 0; s < 2; ++s)
        #pragma unroll
        for (int nt = 0; nt < 4; ++nt) acc[s][nt] = z;

    {
        half8 a[2][2];
        #pragma unroll
        for (int s = 0; s < 2; ++s)
            #pragma unroll
            for (int kg = 0; kg < 2; ++kg) {
                int row = m0 + s * 16 + (l & 15);
                if (row >= N_NODES) row = N_NODES - 1;
                a[s][kg] = afrag_f32(x, row, kg, l);
            }
        const _Float16* pk1 = pk + 2 * 4096;
        #pragma unroll
        for (int nt = 0; nt < 4; ++nt)
            #pragma unroll
            for (int kg = 0; kg < 2; ++kg) {
                half8 b = *(const half8*)(pk1 + ((nt * 2 + kg) * 64 + l) * 8);
                acc[0][nt] = __builtin_amdgcn_mfma_f32_16x16x32_f16(a[0][kg], b, acc[0][nt], 0, 0, 0);
                acc[1][nt] = __builtin_amdgcn_mfma_f32_16x16x32_f16(a[1][kg], b, acc[1][nt], 0, 0, 0);
            }
    }
    {
        half8 a[2][2];
        #pragma unroll
        for (int s = 0; s < 2; ++s)
            #pragma unroll
            for (int kg = 0; kg < 2; ++kg) {
                int row = m0 + s * 16 + (l & 15);
                if (row >= N_NODES) row = N_NODES - 1;
                a[s][kg] = *(const half8*)(hm16 + (size_t)row * 64 + kg * 32 + ((l >> 4) << 3));
            }
        const _Float16* pk2 = pk + 3 * 4096;
        #pragma unroll
        for (int nt = 0; nt < 4; ++nt)
            #pragma unroll
            for (int kg = 0; kg < 2; ++kg) {
                half8 b = *(const half8*)(pk2 + ((nt * 2 + kg) * 64 + l) * 8);
                acc[0][nt] = __builtin_amdgcn_mfma_f32_16x16x32_f16(a[0][kg], b, acc[0][nt], 0, 0, 0);
                acc[1][nt] = __builtin_amdgcn_mfma_f32_16x16x32_f16(a[1][kg], b, acc[1][nt], 0, 0, 0);
            }
    }

    float a1n[4], bcn[4];
    #pragma unroll
    for (int nt = 0; nt < 4; ++nt) {
        int n = nt * 16 + col;
        a1n[nt] = ab1[n];
        bcn[nt] = bcomb[n];
    }
    #pragma unroll
    for (int s = 0; s < 2; ++s)
        #pragma unroll
        for (int r = 0; r < 4; ++r) {
            int row = ((l >> 4) << 2) + r;
            int m = m0 + s * 16 + row;
            int dg = (m < N_NODES) ? (off[m + 1] - off[m]) : 0;
            #pragma unroll
            for (int nt = 0; nt < 4; ++nt) {
                int n = nt * 16 + col;
                float v = acc[s][nt][r] + a1n[nt] + ((dg > 0) ? bcn[nt] : 0.f);
                v = fmaxf(v, 0.f);
                lsh[w][s][row][n ^ ((row & 7) << 3)] = (_Float16)v;
            }
        }
    __syncthreads();

    f32x4 acc2[2][4];
    #pragma unroll
    for (int s = 0; s < 2; ++s)
        #pragma unroll
        for (int nt = 0; nt < 4; ++nt) acc2[s][nt] = z;
    {
        half8 a[2][2];
        #pragma unroll
        for (int s = 0; s < 2; ++s)
            #pragma unroll
            for (int kg = 0; kg < 2; ++kg) {
                int rr = l & 15;
                int c0 = (kg * 32 + ((l >> 4) << 3)) ^ ((rr & 7) << 3);
                a[s][kg] = *(const half8*)&lsh[w][s][rr][c0];
            }
        const _Float16* pk3 = pk + 4 * 4096;
        #pragma unroll
        for (int nt = 0; nt < 4; ++nt)
            #pragma unroll
            for (int kg = 0; kg < 2; ++kg) {
                half8 b = *(const half8*)(pk3 + ((nt * 2 + kg) * 64 + l) * 8);
                acc2[0][nt] = __builtin_amdgcn_mfma_f32_16x16x32_f16(a[0][kg], b, acc2[0][nt], 0, 0, 0);
                acc2[1][nt] = __builtin_amdgcn_mfma_f32_16x16x32_f16(a[1][kg], b, acc2[1][nt], 0, 0, 0);
            }
    }

    float a2n[4];
    #pragma unroll
    for (int nt = 0; nt < 4; ++nt) a2n[nt] = ab2[nt * 16 + col];
    #pragma unroll
    for (int s = 0; s < 2; ++s)
        #pragma unroll
        for (int r = 0; r < 4; ++r) {
            int m = m0 + s * 16 + ((l >> 4) << 2) + r;
            if (m >= N_NODES) continue;
            #pragma unroll
            for (int nt = 0; nt < 4; ++nt)
                out[(size_t)m * 64 + nt * 16 + col] = acc2[s][nt][r] + a2n[nt];
        }
}

extern "C" void kernel_launch(void* const* d_in, const int* in_sizes, int n_in,
                              void* d_out, int out_size, void* d_ws, size_t ws_size,
                              hipStream_t stream) {
    const float* x   = (const float*)d_in[0];
    const int*   ei  = (const int*)d_in[1];
    const int*   ej  = ((const int*)d_in[1]) + N_EDGES;
    const float* pos = (const float*)d_in[2];
    const float* mw1 = (const float*)d_in[3];
    const float* mb1 = (const float*)d_in[4];
    const float* mw2 = (const float*)d_in[5];
    const float* mb2 = (const float*)d_in[6];
    const float* aw1 = (const float*)d_in[7];
    const float* ab1 = (const float*)d_in[8];
    const float* aw2 = (const float*)d_in[9];
    const float* ab2 = (const float*)d_in[10];

    char* ws = (char*)d_ws;
    int*       off    = (int*)(ws + WS_OFF);
    int*       pcur   = (int*)(ws + WS_PCUR);
    int*       sj     = (int*)(ws + WS_SJ);
    float*     bcomb  = (float*)(ws + WS_BCOMB);
    _Float16*  pk     = (_Float16*)(ws + WS_PK);
    _Float16*  Q16    = (_Float16*)(ws + WS_Q);
    int*       binned = (int*)(ws + WS_BIN);
    _Float16*  hm16   = (_Float16*)(ws + WS_HM16);
    _Float16*  P16    = (_Float16*)d_out;     // scratch; k_c2 overwrites d_out
    float*     out    = (float*)d_out;

    hipLaunchKernelGGL(k_setup,  dim3(6), dim3(256), 0, stream,
                       mw1, mw2, mb2, aw1, aw2, pk, bcomb, pcur);
    hipLaunchKernelGGL(k_binpre, dim3(NBB + NBT), dim3(256), 0, stream,
                       ei, ej, pcur, binned, x, pos, mw1, mb1, pk, P16, Q16);
    hipLaunchKernelGGL(k_fill3s, dim3(NPART), dim3(256), 0, stream,
                       binned, pcur, off, sj);
    hipLaunchKernelGGL(k_c1,     dim3((N_NODES + 1) / 2), dim3(128), 0, stream,
                       Q16, off, sj, P16, hm16);
    hipLaunchKernelGGL(k_c2,     dim3(NBT), dim3(256), 0, stream,
                       x, hm16, pk, ab1, bcomb, ab2, off, out);
}